// Round 1
// baseline (327.294 us; speedup 1.0000x reference)
//
#include <hip/hip_runtime.h>
#include <math.h>

// Match numpy's unfused f32 arithmetic as closely as possible (reference is
// checked against a numpy recomputation; fma contraction shifts IoU values at
// the 0.45 decision boundary).
#pragma clang fp contract(off)

#define PNUM   3000
#define NSORT  4096          // next pow2 >= PNUM for bitonic sort
#define NCLS   21
#define TOPK   200
#define WORDS  ((PNUM + 31) / 32)   // 94 mask words
#define BLOCK  1024
#define CONF_T 0.01f
#define NMS_T  0.45f

// One block per (image b = blockIdx.y, class c = blockIdx.x).
// c == 0 (background): zero-fill its 200x5 output rows and exit.
// c >= 1: sort class scores desc (stable via ~idx tiebreak), decode boxes in
// sorted order, greedy NMS with early-exit at TOPK keeps, write [score,box].
__global__ __launch_bounds__(BLOCK) void ssd_nms_kernel(
    const float* __restrict__ loc,     // [B, PNUM, 4]
    const float* __restrict__ conf,    // [B, PNUM, NCLS]
    const float* __restrict__ priors,  // [PNUM, 4]
    float* __restrict__ out)           // [B, NCLS, TOPK, 5]
{
    const int c   = blockIdx.x;
    const int b   = blockIdx.y;
    const int tid = threadIdx.x;

    float* outbase = out + ((size_t)(b * NCLS + c)) * (TOPK * 5);

    if (c == 0) {
        for (int i = tid; i < TOPK * 5; i += BLOCK) outbase[i] = 0.0f;
        return;
    }

    __shared__ unsigned long long s_key[NSORT];   // 32 KB  (score_bits<<32 | ~idx)
    __shared__ float4             s_box[PNUM];    // 48 KB  decoded boxes, sorted order
    __shared__ float              s_area[PNUM];   // 12 KB
    __shared__ unsigned           s_mask[WORDS];  // keep bitmask over sorted positions
    __shared__ int                s_kept[TOPK];   // sorted positions of kept boxes
    __shared__ int                s_cnt, s_cur, s_next, s_nv;

    if (tid == 0) { s_cnt = 0; s_cur = 0; s_nv = 0; }
    __syncthreads();

    // ---- load scores, build sort keys ----
    const float* confb = conf + ((size_t)b * PNUM) * NCLS + c;
    int myvalid = 0;
    for (int i = tid; i < NSORT; i += BLOCK) {
        unsigned long long key = 0ull;
        if (i < PNUM) {
            float s = confb[(size_t)i * NCLS];
            if (s > CONF_T) {
                key = ((unsigned long long)__float_as_uint(s) << 32)
                    | (unsigned)(~i);
                myvalid++;
            }
        }
        s_key[i] = key;
    }
    // wave-reduce valid count, then one LDS atomic per wave
    for (int off = 32; off > 0; off >>= 1) myvalid += __shfl_down(myvalid, off);
    if ((tid & 63) == 0) atomicAdd(&s_nv, myvalid);

    // ---- bitonic sort, descending (invalid/padding keys==0 sink to the end) ----
    for (unsigned k = 2; k <= NSORT; k <<= 1) {
        for (unsigned j = k >> 1; j > 0; j >>= 1) {
            __syncthreads();
            for (unsigned t = tid; t < NSORT / 2; t += BLOCK) {
                unsigned i   = ((t & ~(j - 1)) << 1) | (t & (j - 1));
                unsigned ixj = i | j;
                unsigned long long a  = s_key[i];
                unsigned long long bb = s_key[ixj];
                bool swp = ((i & k) == 0) ? (a < bb) : (a > bb);
                if (swp) { s_key[i] = bb; s_key[ixj] = a; }
            }
        }
    }
    __syncthreads();

    const int nv = s_nv;

    // ---- decode boxes for valid sorted positions (gather by original idx) ----
    const float4* locb = (const float4*)loc + (size_t)b * PNUM;
    const float4* pri4 = (const float4*)priors;
    for (int p = tid; p < nv; p += BLOCK) {
        unsigned idx = ~(unsigned)s_key[p];     // original prior index
        float4 l  = locb[idx];
        float4 pr = pri4[idx];
        float cx = pr.x + l.x * 0.1f * pr.z;
        float cy = pr.y + l.y * 0.1f * pr.w;
        float w  = pr.z * expf(l.z * 0.2f);
        float h  = pr.w * expf(l.w * 0.2f);
        float x1 = cx - 0.5f * w;
        float y1 = cy - 0.5f * h;
        float x2 = x1 + w;
        float y2 = y1 + h;
        s_box[p]  = make_float4(x1, y1, x2, y2);
        s_area[p] = (x2 - x1) * (y2 - y1);      // from corners, like reference
    }

    // ---- init keep bitmask: positions [0, nv) kept ----
    for (int w = tid; w < WORDS; w += BLOCK) {
        int base = w * 32;
        unsigned m = 0u;
        if (base + 32 <= nv)      m = 0xFFFFFFFFu;
        else if (base < nv)       m = (1u << (nv - base)) - 1u;
        s_mask[w] = m;
    }
    __syncthreads();

    // ---- greedy NMS; stop after TOPK keeps (later keeps can't affect output) ----
    const int lane = tid & 63;
    for (;;) {
        if (tid < 64) {   // wave 0: find next surviving candidate >= s_cur
            int cnt = s_cnt;
            int nxt = -1;
            if (cnt < TOPK) {
                int cur = s_cur;
                int w0  = cur >> 5;
                for (int r = 0; r < 2 && nxt < 0; ++r) {   // 2*64 words >= WORDS
                    int w = w0 + r * 64 + lane;
                    unsigned m = 0u;
                    if (w < WORDS) {
                        m = s_mask[w];
                        if (w == w0) m &= ~((1u << (cur & 31)) - 1u);
                    }
                    unsigned long long bal = __ballot(m != 0u);
                    if (bal) {
                        int l = __ffsll(bal) - 1;
                        unsigned mw = (unsigned)__shfl((int)m, l);
                        nxt = ((w0 + r * 64 + l) << 5) + (__ffs(mw) - 1);
                    }
                }
            }
            if (lane == 0) {
                if (nxt >= 0) {
                    s_kept[cnt] = nxt;
                    s_cnt = cnt + 1;
                    s_cur = nxt + 1;
                }
                s_next = nxt;
            }
        }
        __syncthreads();
        int nxt = s_next;
        if (nxt < 0) break;

        float4 bi = s_box[nxt];   // LDS broadcast
        float  ai = s_area[nxt];
        for (int j = nxt + 1 + tid; j < nv; j += BLOCK) {
            if ((s_mask[j >> 5] >> (j & 31)) & 1u) {
                float4 bj = s_box[j];
                float ltx = fmaxf(bi.x, bj.x);
                float lty = fmaxf(bi.y, bj.y);
                float rbx = fminf(bi.z, bj.z);
                float rby = fminf(bi.w, bj.w);
                float iw  = fmaxf(rbx - ltx, 0.0f);
                float ih  = fmaxf(rby - lty, 0.0f);
                float inter = iw * ih;
                float uni   = ai + s_area[j] - inter;
                float iou   = inter / fmaxf(uni, 1e-12f);
                if (iou > NMS_T)
                    atomicAnd(&s_mask[j >> 5], ~(1u << (j & 31)));
            }
        }
        __syncthreads();   // suppression visible before next scan
    }

    // ---- write output rows: kept -> [score, x1,y1,x2,y2], rest -> zeros ----
    const int cnt = s_cnt;
    for (int r = tid; r < TOPK; r += BLOCK) {
        float v0 = 0.f, v1 = 0.f, v2 = 0.f, v3 = 0.f, v4 = 0.f;
        if (r < cnt) {
            int pos = s_kept[r];
            v0 = __uint_as_float((unsigned)(s_key[pos] >> 32));
            float4 bx = s_box[pos];
            v1 = bx.x; v2 = bx.y; v3 = bx.z; v4 = bx.w;
        }
        float* o = outbase + (size_t)r * 5;
        o[0] = v0; o[1] = v1; o[2] = v2; o[3] = v3; o[4] = v4;
    }
}

extern "C" void kernel_launch(void* const* d_in, const int* in_sizes, int n_in,
                              void* d_out, int out_size, void* d_ws, size_t ws_size,
                              hipStream_t stream) {
    const float* loc    = (const float*)d_in[0];
    const float* conf   = (const float*)d_in[1];
    const float* priors = (const float*)d_in[2];
    float* out          = (float*)d_out;
    const int B = in_sizes[0] / (PNUM * 4);   // 8
    dim3 grid(NCLS, B);
    ssd_nms_kernel<<<grid, BLOCK, 0, stream>>>(loc, conf, priors, out);
}

// Round 2
// 255.601 us; speedup vs baseline: 1.2805x; 1.2805x over previous
//
#include <hip/hip_runtime.h>
#include <math.h>

// Match numpy's unfused f32 arithmetic (fma contraction shifts IoU at the
// 0.45 decision boundary). R1 with this pragma matched absmax 0.0.
#pragma clang fp contract(off)

#define PNUM   3000
#define NSORT  4096          // next pow2 >= PNUM for bitonic sort
#define NCLS   21
#define TOPK   200
#define WORDS  ((PNUM + 31) / 32)   // 94 mask words
#define BLOCK  1024
#define CONF_T 0.01f
#define NMS_T  0.45f

__device__ __forceinline__ float iou_f(float4 a, float aa, float4 b, float ab) {
    float ltx = fmaxf(a.x, b.x);
    float lty = fmaxf(a.y, b.y);
    float rbx = fminf(a.z, b.z);
    float rby = fminf(a.w, b.w);
    float iw  = fmaxf(rbx - ltx, 0.0f);
    float ih  = fmaxf(rby - lty, 0.0f);
    float inter = iw * ih;
    float uni   = aa + ab - inter;
    return inter / fmaxf(uni, 1e-12f);
}

// One block per (image b, class c). Batched-greedy NMS: each round gathers the
// next <=64 SURVIVORS (everything between them is already suppressed), resolves
// greedy among them in-register (exact: a member's fate depends only on
// higher-ranked members of the same batch), then one parallel sweep suppresses
// all later candidates against the round's keeps. ~200 serial keep-iterations
// collapse to ~10-25 rounds.
__global__ __launch_bounds__(BLOCK) void ssd_nms_kernel(
    const float* __restrict__ loc,     // [B, PNUM, 4]
    const float* __restrict__ conf,    // [B, PNUM, NCLS]
    const float* __restrict__ priors,  // [PNUM, 4]
    float* __restrict__ out)           // [B, NCLS, TOPK, 5]
{
    const int c   = blockIdx.x;
    const int b   = blockIdx.y;
    const int tid = threadIdx.x;

    float* outbase = out + ((size_t)(b * NCLS + c)) * (TOPK * 5);

    if (c == 0) {
        for (int i = tid; i < TOPK * 5; i += BLOCK) outbase[i] = 0.0f;
        return;
    }

    __shared__ unsigned long long s_key[NSORT];   // 32 KB  (score_bits<<32 | ~idx)
    __shared__ float4             s_box[PNUM];    // 48 KB  decoded boxes, sorted order
    __shared__ float              s_area[PNUM];   // 12 KB
    __shared__ unsigned           s_mask[WORDS];  // survivor bitmask (sorted positions)
    __shared__ unsigned long long s_supp[64];     // per-batch-lane suppression bits
    __shared__ float4             s_bbox[64];     // batch candidate boxes
    __shared__ float              s_barea[64];
    __shared__ float              s_bscore[64];
    __shared__ float4             s_kbox[64];     // batch KEPT boxes (compacted)
    __shared__ float              s_karea[64];
    __shared__ int s_nv, s_cur, s_bn, s_cnt, s_kn, s_done;

    if (tid == 0) { s_nv = 0; s_cur = 0; s_cnt = 0; s_done = 0; }
    __syncthreads();

    // ---- load scores, build sort keys ----
    const float* confb = conf + ((size_t)b * PNUM) * NCLS + c;
    int myvalid = 0;
    for (int i = tid; i < NSORT; i += BLOCK) {
        unsigned long long key = 0ull;
        if (i < PNUM) {
            float s = confb[(size_t)i * NCLS];
            if (s > CONF_T) {
                key = ((unsigned long long)__float_as_uint(s) << 32)
                    | (unsigned)(~i);
                myvalid++;
            }
        }
        s_key[i] = key;
    }
    for (int off = 32; off > 0; off >>= 1) myvalid += __shfl_down(myvalid, off);
    if ((tid & 63) == 0) atomicAdd(&s_nv, myvalid);

    // ---- bitonic sort, descending (invalid/padding keys==0 sink to the end) ----
    for (unsigned k = 2; k <= NSORT; k <<= 1) {
        for (unsigned j = k >> 1; j > 0; j >>= 1) {
            __syncthreads();
            for (unsigned t = tid; t < NSORT / 2; t += BLOCK) {
                unsigned i   = ((t & ~(j - 1)) << 1) | (t & (j - 1));
                unsigned ixj = i | j;
                unsigned long long a  = s_key[i];
                unsigned long long bb = s_key[ixj];
                bool swp = ((i & k) == 0) ? (a < bb) : (a > bb);
                if (swp) { s_key[i] = bb; s_key[ixj] = a; }
            }
        }
    }
    __syncthreads();

    const int nv = s_nv;

    // ---- decode boxes for valid sorted positions ----
    const float4* locb = (const float4*)loc + (size_t)b * PNUM;
    const float4* pri4 = (const float4*)priors;
    for (int p = tid; p < nv; p += BLOCK) {
        unsigned idx = ~(unsigned)s_key[p];
        float4 l  = locb[idx];
        float4 pr = pri4[idx];
        float cx = pr.x + l.x * 0.1f * pr.z;
        float cy = pr.y + l.y * 0.1f * pr.w;
        float w  = pr.z * expf(l.z * 0.2f);
        float h  = pr.w * expf(l.w * 0.2f);
        float x1 = cx - 0.5f * w;
        float y1 = cy - 0.5f * h;
        float x2 = x1 + w;
        float y2 = y1 + h;
        s_box[p]  = make_float4(x1, y1, x2, y2);
        s_area[p] = (x2 - x1) * (y2 - y1);
    }
    for (int w = tid; w < WORDS; w += BLOCK) {
        int base = w * 32;
        unsigned m = 0u;
        if (base + 32 <= nv)      m = 0xFFFFFFFFu;
        else if (base < nv)       m = (1u << (nv - base)) - 1u;
        s_mask[w] = m;
    }
    __syncthreads();

    const int lane = tid & 63;

    for (;;) {
        // ---- A: wave0 gathers the next <=64 survivors into batch slots ----
        if (tid < 64) {
            s_supp[lane] = 0ull;
            int cur = s_cur;
            int w0  = cur >> 5;
            int collected = 0;
            // 2 rounds x 64 words >= WORDS, so <64 collected means truly exhausted
            for (int r = 0; r < 2 && collected < 64; ++r) {
                int w = w0 + (r << 6) + lane;
                unsigned m = 0u;
                if (w < WORDS) {
                    m = s_mask[w];
                    if (w == w0) m &= ~((1u << (cur & 31)) - 1u);
                }
                int pc   = __popc(m);
                int incl = pc;
                for (int d = 1; d < 64; d <<= 1) {
                    int v = __shfl_up(incl, d);
                    if (lane >= d) incl += v;
                }
                int total = __shfl(incl, 63);
                int base  = collected + (incl - pc);
                unsigned mm = m;
                while (mm && base < 64) {
                    int p = __ffs(mm) - 1; mm &= mm - 1;
                    int pos = (w << 5) + p;
                    s_bbox[base]   = s_box[pos];
                    s_barea[base]  = s_area[pos];
                    s_bscore[base] = __uint_as_float((unsigned)(s_key[pos] >> 32));
                    if (base == 63) s_cur = pos + 1;   // advance past batch
                    base++;
                }
                collected += total;
            }
            if (lane == 0) {
                s_bn = collected < 64 ? collected : 64;
                if (collected < 64) s_cur = nv;       // exhausted
            }
        }
        __syncthreads();
        const int bn = s_bn;
        if (bn == 0) break;

        // ---- C: pairwise suppression bits within batch (all 16 waves) ----
        {
            int L = tid & 63, g = tid >> 6;
            if (L < bn) {
                float4 bl = s_bbox[L];
                float  al = s_barea[L];
                unsigned long long bits = 0ull;
                int M0 = g << 2;
                for (int q = 0; q < 4; ++q) {
                    int M = M0 + q;
                    if (M < L) {
                        if (iou_f(s_bbox[M], s_barea[M], bl, al) > NMS_T)
                            bits |= (1ull << M);
                    }
                }
                if (bits) atomicOr(&s_supp[L], bits);
            }
        }
        __syncthreads();

        // ---- D: wave0 resolves greedy within batch, emits kept rows ----
        if (tid < 64) {
            unsigned long long sup  = s_supp[lane];
            unsigned long long kept = 0ull;
            for (int M = 0; M < bn; ++M) {
                unsigned long long supM = __shfl(sup, M);
                if ((supM & kept) == 0ull) kept |= (1ull << M);
            }
            int cnt   = s_cnt;
            int keptN = __popcll(kept);
            bool me   = (lane < bn) && ((kept >> lane) & 1ull);
            int krank = __popcll(kept & ((1ull << lane) - 1ull));
            if (me) {
                s_kbox[krank]  = s_bbox[lane];
                s_karea[krank] = s_barea[lane];
                int r = cnt + krank;
                if (r < TOPK) {
                    float4 bx = s_bbox[lane];
                    float* o  = outbase + (size_t)r * 5;
                    o[0] = s_bscore[lane];
                    o[1] = bx.x; o[2] = bx.y; o[3] = bx.z; o[4] = bx.w;
                }
            }
            if (lane == 0) {
                s_kn   = keptN;
                s_cnt  = cnt + keptN;
                s_done = (cnt + keptN >= TOPK) ? 1 : 0;
            }
        }
        __syncthreads();
        if (s_done) break;   // later candidates can't affect the first TOPK rows

        // ---- E: sweep all later candidates vs this round's keeps ----
        {
            const int kn = s_kn;
            if (kn > 0) {
                const int start = s_cur;
                for (int jj = start + tid; jj < nv; jj += BLOCK) {
                    if (!((s_mask[jj >> 5] >> (jj & 31)) & 1u)) continue;
                    float4 bj = s_box[jj];
                    float  aj = s_area[jj];
                    for (int M = 0; M < kn; ++M) {
                        if (iou_f(s_kbox[M], s_karea[M], bj, aj) > NMS_T) {
                            atomicAnd(&s_mask[jj >> 5], ~(1u << (jj & 31)));
                            break;
                        }
                    }
                }
            }
        }
        __syncthreads();
    }

    // ---- zero the unwritten tail rows ----
    const int cf = s_cnt < TOPK ? s_cnt : TOPK;
    for (int r = cf + tid; r < TOPK; r += BLOCK) {
        float* o = outbase + (size_t)r * 5;
        o[0] = 0.f; o[1] = 0.f; o[2] = 0.f; o[3] = 0.f; o[4] = 0.f;
    }
}

extern "C" void kernel_launch(void* const* d_in, const int* in_sizes, int n_in,
                              void* d_out, int out_size, void* d_ws, size_t ws_size,
                              hipStream_t stream) {
    const float* loc    = (const float*)d_in[0];
    const float* conf   = (const float*)d_in[1];
    const float* priors = (const float*)d_in[2];
    float* out          = (float*)d_out;
    const int B = in_sizes[0] / (PNUM * 4);   // 8
    dim3 grid(NCLS, B);
    ssd_nms_kernel<<<grid, BLOCK, 0, stream>>>(loc, conf, priors, out);
}

// Round 3
// 141.239 us; speedup vs baseline: 2.3173x; 1.8097x over previous
//
#include <hip/hip_runtime.h>
#include <math.h>

// Match numpy's unfused f32 arithmetic (fma contraction shifts IoU at the
// 0.45 decision boundary). R1/R2 with this pragma matched absmax 0.0.
#pragma clang fp contract(off)

#define PNUM    3000
#define NCLS    21
#define TOPK    200
#define BLOCK   1024
#define CHUNK   1024                 // chunk capacity (pow2, == BLOCK)
#define CWORDS  (CHUNK / 32)         // 32 mask words
#define NMS_T   0.45f
#define LO_BITS 0x3C23D70Bu          // smallest float bits strictly > 0.01f
#define MAXKEEP (TOPK + 64)          // cnt<200 before a round, +<=64 keeps

__device__ __forceinline__ float iou_f(float4 a, float aa, float4 b, float ab) {
    float ltx = fmaxf(a.x, b.x);
    float lty = fmaxf(a.y, b.y);
    float rbx = fminf(a.z, b.z);
    float rby = fminf(a.w, b.w);
    float iw  = fmaxf(rbx - ltx, 0.0f);
    float ih  = fmaxf(rby - lty, 0.0f);
    float inter = iw * ih;
    float uni   = aa + ab - inter;
    return inter / fmaxf(uni, 1e-12f);
}

// One block per (image b, class c). Top-chunk selection (binary search on
// score bits held in registers) -> compact -> 1024-key bitonic sort -> decode
// chunk only -> batched greedy NMS (exact). Refill with the next score-range
// chunk (swept against all committed keeps) preserves exact reference order:
// score ties never straddle a chunk boundary, and in-chunk order uses the
// full (score desc, idx asc) key.
__global__ __launch_bounds__(BLOCK) void ssd_nms_kernel(
    const float* __restrict__ loc,     // [B, PNUM, 4]
    const float* __restrict__ conf,    // [B, PNUM, NCLS]
    const float* __restrict__ priors,  // [PNUM, 4]
    float* __restrict__ out)           // [B, NCLS, TOPK, 5]
{
    const int c   = blockIdx.x;
    const int b   = blockIdx.y;
    const int tid = threadIdx.x;

    float* outbase = out + ((size_t)(b * NCLS + c)) * (TOPK * 5);

    if (c == 0) {
        for (int i = tid; i < TOPK * 5; i += BLOCK) outbase[i] = 0.0f;
        return;
    }

    __shared__ unsigned long long s_sort[CHUNK];   // 8 KB  (score<<32 | ~idx)
    __shared__ float4             s_box[CHUNK];    // 16 KB decoded chunk boxes
    __shared__ float              s_area[CHUNK];   // 4 KB
    __shared__ float4             s_kb[MAXKEEP];   // all committed keep boxes
    __shared__ float              s_ka[MAXKEEP];
    __shared__ unsigned           s_mask[CWORDS];  // chunk survivor bitmask
    __shared__ unsigned long long s_supp[64];      // in-batch suppression bits
    __shared__ float4             s_bbox[64];
    __shared__ float              s_barea[64], s_bscore[64];
    __shared__ int s_red, s_m, s_cur, s_bn, s_cnt, s_kn, s_done;

    const int lane = tid & 63;

    // ---- per-thread score bits in REGISTERS (elements tid + q*1024) ----
    unsigned hb[4];
    const float* confb = conf + ((size_t)b * PNUM) * NCLS + c;
    #pragma unroll
    for (int q = 0; q < 4; ++q) {
        int i = tid + (q << 10);
        unsigned h = 0u;
        if (i < PNUM) {
            float s = confb[(size_t)i * NCLS];
            if (s > 0.01f) h = __float_as_uint(s);
        }
        hb[q] = h;
    }
    if (tid == 0) s_cnt = 0;

    // scores are uniform [0,1): all valid sbits < bits(1.0)+1
    unsigned long long Thi = 0x3F800001ull;

    for (;;) {   // ---- chunk loop ----
        // binary search largest chunk [T, Thi) with count <= CHUNK
        unsigned long long blo = LO_BITS, bhi = Thi, T = Thi;
        int M = 0;
        while (blo < bhi) {
            unsigned long long mid = (blo + bhi) >> 1;
            __syncthreads();
            if (tid == 0) s_red = 0;
            __syncthreads();
            int lc = 0;
            #pragma unroll
            for (int q = 0; q < 4; ++q) {
                unsigned long long sb = hb[q];
                lc += (sb >= mid && sb < Thi) ? 1 : 0;
            }
            for (int d = 32; d > 0; d >>= 1) lc += __shfl_down(lc, d);
            if (lane == 0 && lc) atomicAdd(&s_red, lc);
            __syncthreads();
            int n = s_red;                 // uniform across block
            if (n <= CHUNK) {
                T = mid; M = n;            // invariant: M == count([T, Thi))
                if (n >= CHUNK / 2) break; // wide acceptance band
                bhi = mid;
            } else {
                blo = mid + 1;
            }
        }
        if (M == 0) break;                 // no candidates remain

        // ---- compact chunk candidates into s_sort (order irrelevant) ----
        __syncthreads();
        if (tid == 0) s_m = 0;
        s_sort[tid] = 0ull;                // pad entries sort last (desc)
        __syncthreads();
        #pragma unroll
        for (int q = 0; q < 4; ++q) {
            unsigned long long sb = hb[q];
            bool pred = (sb >= T && sb < Thi);
            unsigned long long bal = __ballot(pred);
            int wb = 0;
            if (lane == 0 && bal) wb = atomicAdd(&s_m, (int)__popcll(bal));
            wb = __shfl(wb, 0);
            if (pred) {
                int dst = wb + (int)__popcll(bal & ((1ull << lane) - 1ull));
                int i = tid + (q << 10);
                s_sort[dst] = (sb << 32) | (unsigned)(~i);
            }
        }

        // ---- bitonic sort CHUNK u64 keys, descending ----
        for (unsigned k = 2; k <= CHUNK; k <<= 1) {
            for (unsigned j = k >> 1; j > 0; j >>= 1) {
                __syncthreads();
                if (tid < CHUNK / 2) {
                    unsigned i = (((unsigned)tid & ~(j - 1)) << 1) | ((unsigned)tid & (j - 1));
                    unsigned ixj = i | j;
                    unsigned long long a  = s_sort[i];
                    unsigned long long bb = s_sort[ixj];
                    bool swp = ((i & k) == 0) ? (a < bb) : (a > bb);
                    if (swp) { s_sort[i] = bb; s_sort[ixj] = a; }
                }
            }
        }
        __syncthreads();

        // ---- decode chunk boxes + init survivor mask ----
        {
            int p = tid;
            if (p < M) {
                unsigned idx = ~(unsigned)s_sort[p];   // original prior index
                float4 l  = ((const float4*)loc)[(size_t)b * PNUM + idx];
                float4 pr = ((const float4*)priors)[idx];
                float cx = pr.x + l.x * 0.1f * pr.z;
                float cy = pr.y + l.y * 0.1f * pr.w;
                float w  = pr.z * expf(l.z * 0.2f);
                float h  = pr.w * expf(l.w * 0.2f);
                float x1 = cx - 0.5f * w;
                float y1 = cy - 0.5f * h;
                float x2 = x1 + w;
                float y2 = y1 + h;
                s_box[p]  = make_float4(x1, y1, x2, y2);
                s_area[p] = (x2 - x1) * (y2 - y1);
            }
            if (tid < CWORDS) {
                int base = tid * 32;
                unsigned m = 0u;
                if (base + 32 <= M) m = 0xFFFFFFFFu;
                else if (base < M)  m = (1u << (M - base)) - 1u;
                s_mask[tid] = m;
            }
            if (tid == 0) s_cur = 0;
        }
        __syncthreads();

        // ---- refill chunks: sweep vs ALL previously committed keeps ----
        {
            int kall = s_cnt;
            if (kall > 0) {
                int j = tid;
                if (j < M) {
                    float4 bj = s_box[j];
                    float  aj = s_area[j];
                    for (int K = 0; K < kall; ++K) {
                        if (iou_f(s_kb[K], s_ka[K], bj, aj) > NMS_T) {
                            atomicAnd(&s_mask[j >> 5], ~(1u << (j & 31)));
                            break;
                        }
                    }
                }
                __syncthreads();
            }
        }

        // ---- batched greedy rounds within chunk ----
        for (;;) {
            // A: wave0 gathers next <=64 survivors
            if (tid < 64) {
                s_supp[lane] = 0ull;
                int cur = s_cur;
                unsigned m = 0u;
                if (lane < CWORDS) {
                    m = s_mask[lane];
                    int cw = cur >> 5;
                    if (lane < cw) m = 0u;
                    else if (lane == cw) m &= ~((1u << (cur & 31)) - 1u);
                }
                int pc = __popc(m);
                int incl = pc;
                for (int d = 1; d < 64; d <<= 1) {
                    int v = __shfl_up(incl, d);
                    if (lane >= d) incl += v;
                }
                int excl  = incl - pc;
                int total = __shfl(incl, 63);
                int bn    = total < 64 ? total : 64;
                unsigned mm = m; int r = excl;
                while (mm && r < 64) {
                    int bpos = __ffs(mm) - 1; mm &= mm - 1;
                    int pos  = (lane << 5) + bpos;
                    s_bbox[r]   = s_box[pos];
                    s_barea[r]  = s_area[pos];
                    s_bscore[r] = __uint_as_float((unsigned)(s_sort[pos] >> 32));
                    if (r == bn - 1) s_cur = pos + 1;
                    r++;
                }
                if (lane == 0) s_bn = bn;
            }
            __syncthreads();
            const int bn = s_bn;
            if (bn == 0) break;

            // C: in-batch pairwise suppression bits (all 16 waves)
            {
                int L = tid & 63, g = tid >> 6;
                if (L < bn) {
                    float4 bl = s_bbox[L];
                    float  al = s_barea[L];
                    unsigned long long bits = 0ull;
                    int M0 = g << 2;
                    #pragma unroll
                    for (int q2 = 0; q2 < 4; ++q2) {
                        int Mi = M0 + q2;
                        if (Mi < L) {
                            if (iou_f(s_bbox[Mi], s_barea[Mi], bl, al) > NMS_T)
                                bits |= (1ull << Mi);
                        }
                    }
                    if (bits) atomicOr(&s_supp[L], bits);
                }
            }
            __syncthreads();

            // D: wave0 resolves greedy recurrence, emits rows, appends keeps
            if (tid < 64) {
                unsigned long long sup  = s_supp[lane];
                unsigned long long kept = 0ull;
                for (int Mi = 0; Mi < bn; ++Mi) {
                    unsigned long long supM = __shfl(sup, Mi);
                    if ((supM & kept) == 0ull) kept |= (1ull << Mi);
                }
                int cnt   = s_cnt;
                int keptN = __popcll(kept);
                bool me   = (lane < bn) && ((kept >> lane) & 1ull);
                int krank = (int)__popcll(kept & ((1ull << lane) - 1ull));
                if (me) {
                    int kid = cnt + krank;           // < MAXKEEP by construction
                    s_kb[kid] = s_bbox[lane];
                    s_ka[kid] = s_barea[lane];
                    if (kid < TOPK) {
                        float4 bx = s_bbox[lane];
                        float* o  = outbase + (size_t)kid * 5;
                        o[0] = s_bscore[lane];
                        o[1] = bx.x; o[2] = bx.y; o[3] = bx.z; o[4] = bx.w;
                    }
                }
                if (lane == 0) {
                    s_kn   = keptN;
                    s_cnt  = cnt + keptN;
                    s_done = (cnt + keptN >= TOPK) ? 1 : 0;
                }
            }
            __syncthreads();
            if (s_done) break;   // first TOPK rows fixed

            // E: sweep rest of chunk vs this round's keeps
            {
                int kn = s_kn;
                if (kn > 0) {
                    int kbase = s_cnt - kn;
                    int j = s_cur + tid;
                    if (j < M && ((s_mask[j >> 5] >> (j & 31)) & 1u)) {
                        float4 bj = s_box[j];
                        float  aj = s_area[j];
                        for (int Mi = 0; Mi < kn; ++Mi) {
                            if (iou_f(s_kb[kbase + Mi], s_ka[kbase + Mi], bj, aj) > NMS_T) {
                                atomicAnd(&s_mask[j >> 5], ~(1u << (j & 31)));
                                break;
                            }
                        }
                    }
                }
            }
            __syncthreads();
        }

        if (s_cnt >= TOPK) break;
        if (T <= LO_BITS) break;   // everything consumed
        Thi = T;                   // next chunk: scores in [T2, T)
    }

    // ---- zero unwritten tail rows ----
    __syncthreads();
    const int cf = s_cnt < TOPK ? s_cnt : TOPK;
    for (int r = cf + tid; r < TOPK; r += BLOCK) {
        float* o = outbase + (size_t)r * 5;
        o[0] = 0.f; o[1] = 0.f; o[2] = 0.f; o[3] = 0.f; o[4] = 0.f;
    }
}

extern "C" void kernel_launch(void* const* d_in, const int* in_sizes, int n_in,
                              void* d_out, int out_size, void* d_ws, size_t ws_size,
                              hipStream_t stream) {
    const float* loc    = (const float*)d_in[0];
    const float* conf   = (const float*)d_in[1];
    const float* priors = (const float*)d_in[2];
    float* out          = (float*)d_out;
    const int B = in_sizes[0] / (PNUM * 4);   // 8
    dim3 grid(NCLS, B);
    ssd_nms_kernel<<<grid, BLOCK, 0, stream>>>(loc, conf, priors, out);
}

// Round 4
// 115.884 us; speedup vs baseline: 2.8243x; 1.2188x over previous
//
#include <hip/hip_runtime.h>
#include <math.h>

// Match numpy's unfused f32 arithmetic (fma contraction shifts IoU at the
// 0.45 decision boundary). R1-R3 with this pragma matched absmax 0.0.
#pragma clang fp contract(off)

#define PNUM    3000
#define NCLS    21
#define TOPK    200
#define BLOCK   1024
#define CHUNK   1024
#define NMS_T   0.45f
#define LO_BITS 0x3C23D70Bu          // smallest float bits strictly > 0.01f
#define T0_BITS 0x3F333333u          // bits(0.70f): first-probe threshold
#define HI_BITS 0x3F800001u          // > bits of any score in [0,1]
#define MAXKEEP (TOPK + 64)

__device__ __forceinline__ float iou_f(float4 a, float aa, float4 b, float ab) {
    float ltx = fmaxf(a.x, b.x);
    float lty = fmaxf(a.y, b.y);
    float rbx = fminf(a.z, b.z);
    float rby = fminf(a.w, b.w);
    float iw  = fmaxf(rbx - ltx, 0.0f);
    float ih  = fmaxf(rby - lty, 0.0f);
    float inter = iw * ih;
    float uni   = aa + ab - inter;           // keeper area first (ref order)
    return inter / fmaxf(uni, 1e-12f);
}

// One block per (image b, class c). Score-range chunk selection -> register
// bitonic sort (shfl for j<64, ping-pong LDS for j>=64: 10 barriers) ->
// LAZY greedy NMS: each round takes the next 64 sorted positions, checks them
// vs committed keeps + higher-ranked in-batch members (exact greedy
// recurrence), resolves in wave0, emits rows. 2 barriers/round, no survivor
// mask, no chunk sweep. Refill chunks continue seamlessly (committed-keep
// check covers cross-chunk suppression).
__global__ __launch_bounds__(BLOCK) void ssd_nms_kernel(
    const float* __restrict__ loc,     // [B, PNUM, 4]
    const float* __restrict__ conf,    // [B, PNUM, NCLS]
    const float* __restrict__ priors,  // [PNUM, 4]
    float* __restrict__ out)           // [B, NCLS, TOPK, 5]
{
    const int c   = blockIdx.x;
    const int b   = blockIdx.y;
    const int tid = threadIdx.x;

    float* outbase = out + ((size_t)(b * NCLS + c)) * (TOPK * 5);

    if (c == 0) {
        for (int i = tid; i < TOPK * 5; i += BLOCK) outbase[i] = 0.0f;
        return;
    }

    __shared__ unsigned long long s_bufA[CHUNK];  // 8 KB  sort ping
    __shared__ unsigned long long s_bufB[CHUNK];  // 8 KB  sort pong
    __shared__ float4             s_box[CHUNK];   // 16 KB decoded chunk boxes
    __shared__ float              s_area[CHUNK];  // 4 KB
    __shared__ float              s_score[CHUNK]; // 4 KB
    __shared__ float4             s_kb[MAXKEEP];  // committed keep boxes
    __shared__ float              s_ka[MAXKEEP];
    __shared__ unsigned long long s_supp[64];     // in-batch suppression bits
    __shared__ int                s_supc[64];     // suppressed-by-committed flag
    __shared__ int s_red, s_m, s_cnt, s_done;

    const int lane = tid & 63;
    const int wav  = tid >> 6;

    // ---- per-thread score bits in registers (elements tid + q*1024) ----
    unsigned hb[4];
    const float* confb = conf + ((size_t)b * PNUM) * NCLS + c;
    #pragma unroll
    for (int q = 0; q < 4; ++q) {
        int i = tid + (q << 10);
        unsigned h = 0u;
        if (i < PNUM) {
            float s = confb[(size_t)i * NCLS];
            if (s > 0.01f) h = __float_as_uint(s);
        }
        hb[q] = h;
    }
    if (tid < 64) { s_supp[lane] = 0ull; s_supc[lane] = 0; }
    if (tid == 0) { s_cnt = 0; s_done = 0; }

    unsigned Thi = HI_BITS;
    bool first = true;
    bool done  = false;

    for (;;) {   // ================= chunk loop =================
        // ---- select threshold T: fixed probe first, bisection fallback ----
        unsigned T = Thi; int M = 0;
        {
            unsigned blo = LO_BITS, bhi = Thi;
            bool fp = first;
            while (blo < bhi) {
                unsigned mid = fp ? T0_BITS : (blo + ((bhi - blo) >> 1));
                __syncthreads();
                if (tid == 0) s_red = 0;
                __syncthreads();
                int lc = 0;
                #pragma unroll
                for (int q = 0; q < 4; ++q)
                    lc += (hb[q] >= mid && hb[q] < Thi) ? 1 : 0;
                for (int d = 32; d > 0; d >>= 1) lc += __shfl_down(lc, d);
                if (lane == 0 && lc) atomicAdd(&s_red, lc);
                __syncthreads();
                int n = s_red;                    // block-uniform
                if (n <= CHUNK && !(fp && n == 0)) {
                    T = mid; M = n;
                    if (fp || n >= CHUNK / 2) break;
                    bhi = mid;
                } else if (n > CHUNK) {
                    blo = mid + 1;
                }
                fp = false;
            }
        }
        if (M == 0) break;                        // nothing left

        // ---- compact candidates [T, Thi) into s_bufA (order irrelevant) ----
        __syncthreads();
        if (tid == 0) s_m = 0;
        s_bufA[tid] = 0ull;                       // pad keys sort last (desc)
        __syncthreads();
        #pragma unroll
        for (int q = 0; q < 4; ++q) {
            unsigned sb = hb[q];
            bool pred = (sb >= T && sb < Thi);
            unsigned long long bal = __ballot(pred);
            int wb = 0;
            if (lane == 0 && bal) wb = atomicAdd(&s_m, (int)__popcll(bal));
            wb = __shfl(wb, 0);
            if (pred) {
                int dst = wb + (int)__popcll(bal & ((1ull << lane) - 1ull));
                int i = tid + (q << 10);
                s_bufA[dst] = ((unsigned long long)sb << 32) | (unsigned)(~i);
            }
        }
        __syncthreads();

        // ---- register bitonic sort, descending; shfl_xor for j<64,
        //      ping-pong LDS exchange (1 barrier each) for j>=64 ----
        unsigned long long key = s_bufA[tid];
        int parity = 0;
        for (unsigned k = 2; k <= CHUNK; k <<= 1) {
            for (unsigned j = k >> 1; j > 0; j >>= 1) {
                unsigned long long pk;
                if (j >= 64) {
                    unsigned long long* buf = parity ? s_bufB : s_bufA;
                    buf[tid] = key;
                    __syncthreads();
                    pk = buf[tid ^ j];
                    parity ^= 1;
                } else {
                    pk = __shfl_xor(key, (int)j, 64);
                }
                bool takeMax  = (((tid & j) == 0) == ((tid & k) == 0));
                bool pGreater = pk > key;
                if (takeMax == pGreater) key = pk;
            }
        }
        // no barrier needed: each thread reads only its own decoded slots below
        // after the round-phase barrier; but decode writes must be published
        // before rounds -> one barrier after decode.

        // ---- decode chunk boxes (thread tid == sorted rank tid) ----
        if (key != 0ull) {
            unsigned idx = ~(unsigned)key;        // original prior index
            float4 l  = ((const float4*)loc)[(size_t)b * PNUM + idx];
            float4 pr = ((const float4*)priors)[idx];
            float cx = pr.x + l.x * 0.1f * pr.z;
            float cy = pr.y + l.y * 0.1f * pr.w;
            float w  = pr.z * expf(l.z * 0.2f);
            float h  = pr.w * expf(l.w * 0.2f);
            float x1 = cx - 0.5f * w;
            float y1 = cy - 0.5f * h;
            float x2 = x1 + w;
            float y2 = y1 + h;
            s_box[tid]   = make_float4(x1, y1, x2, y2);
            s_area[tid]  = (x2 - x1) * (y2 - y1);
            s_score[tid] = __uint_as_float((unsigned)(key >> 32));
        }
        __syncthreads();

        // ---- lazy greedy rounds: 64 sorted positions per round ----
        int pos = 0;
        while (pos < M) {
            int bn  = M - pos; if (bn > 64) bn = 64;
            int cnt = s_cnt;                      // published before last barrier

            // CK: all 16 waves check candidates vs committed keeps + in-batch
            if (lane < bn) {
                float4 bL = s_box[pos + lane];
                float  aL = s_area[pos + lane];
                for (int K = wav; K < cnt; K += 16) {
                    if (iou_f(s_kb[K], s_ka[K], bL, aL) > NMS_T) {
                        atomicOr(&s_supc[lane], 1);
                        break;
                    }
                }
                unsigned long long bits = 0ull;
                int M0 = wav << 2;
                #pragma unroll
                for (int q2 = 0; q2 < 4; ++q2) {
                    int Mi = M0 + q2;
                    if (Mi < lane) {
                        if (iou_f(s_box[pos + Mi], s_area[pos + Mi], bL, aL) > NMS_T)
                            bits |= (1ull << Mi);
                    }
                }
                if (bits) atomicOr(&s_supp[lane], bits);
            }
            __syncthreads();

            // D: wave0 resolves greedy recurrence, emits rows, appends keeps
            if (tid < 64) {
                unsigned long long sup      = s_supp[lane];
                unsigned long long deadmask = __ballot(s_supc[lane] != 0);
                unsigned long long kept     = 0ull;
                for (int Mi = 0; Mi < bn; ++Mi) {
                    unsigned long long supM = __shfl(sup, Mi, 64);
                    if (!((deadmask >> Mi) & 1ull) && !(supM & kept))
                        kept |= (1ull << Mi);
                }
                int keptN = (int)__popcll(kept);
                bool me   = (lane < bn) && ((kept >> lane) & 1ull);
                int krank = (int)__popcll(kept & ((1ull << lane) - 1ull));
                if (me) {
                    int kid = cnt + krank;        // < MAXKEEP by construction
                    float4 bx = s_box[pos + lane];
                    s_kb[kid] = bx;
                    s_ka[kid] = s_area[pos + lane];
                    if (kid < TOPK) {
                        float* o = outbase + (size_t)kid * 5;
                        o[0] = s_score[pos + lane];
                        o[1] = bx.x; o[2] = bx.y; o[3] = bx.z; o[4] = bx.w;
                    }
                }
                s_supp[lane] = 0ull;              // reset for next round
                s_supc[lane] = 0;
                if (lane == 0) {
                    s_cnt  = cnt + keptN;
                    s_done = (cnt + keptN >= TOPK) ? 1 : 0;
                }
            }
            __syncthreads();
            if (s_done) { done = true; break; }   // first TOPK rows fixed
            pos += bn;
        }

        if (done) break;
        if (T <= LO_BITS) break;                  // all candidates consumed
        Thi = T;                                  // next chunk: scores in [?, T)
        first = false;
    }

    // ---- zero unwritten tail rows ----
    __syncthreads();
    const int cf = s_cnt < TOPK ? s_cnt : TOPK;
    for (int r = cf + tid; r < TOPK; r += BLOCK) {
        float* o = outbase + (size_t)r * 5;
        o[0] = 0.f; o[1] = 0.f; o[2] = 0.f; o[3] = 0.f; o[4] = 0.f;
    }
}

extern "C" void kernel_launch(void* const* d_in, const int* in_sizes, int n_in,
                              void* d_out, int out_size, void* d_ws, size_t ws_size,
                              hipStream_t stream) {
    const float* loc    = (const float*)d_in[0];
    const float* conf   = (const float*)d_in[1];
    const float* priors = (const float*)d_in[2];
    float* out          = (float*)d_out;
    const int B = in_sizes[0] / (PNUM * 4);   // 8
    dim3 grid(NCLS, B);
    ssd_nms_kernel<<<grid, BLOCK, 0, stream>>>(loc, conf, priors, out);
}